// Round 10
// baseline (1021.867 us; speedup 1.0000x reference)
//
#include <hip/hip_runtime.h>
#include <stdint.h>

// Problem constants
#define VOCAB 50000
#define EMBD  128
#define HID   256
#define G4    1024   // 4*HID
#define BATCH 256
#define TSEQ  512
#define OUTD  64

typedef __attribute__((ext_vector_type(4))) float f32x4;
typedef __attribute__((ext_vector_type(8))) short short8;
typedef __attribute__((ext_vector_type(4))) unsigned short ushort4_t;
typedef __attribute__((ext_vector_type(8))) unsigned short ushort8_t;

__device__ inline unsigned short f2bf(float f) {
  unsigned u = __float_as_uint(f);
  u += 0x7fffu + ((u >> 16) & 1u);     // round-nearest-even
  return (unsigned short)(u >> 16);
}
__device__ inline float bf2f(unsigned short u) {
  return __uint_as_float(((unsigned)u) << 16);
}
__device__ inline short8 pack2(f32x4 a, f32x4 b) {
  short8 r;
  r[0] = (short)f2bf(a[0]); r[1] = (short)f2bf(a[1]);
  r[2] = (short)f2bf(a[2]); r[3] = (short)f2bf(a[3]);
  r[4] = (short)f2bf(b[0]); r[5] = (short)f2bf(b[1]);
  r[6] = (short)f2bf(b[2]); r[7] = (short)f2bf(b[3]);
  return r;
}

// LDS-only barrier: h double-buffer needs only LDS ordering; global prefetch
// loads stay in flight across it.
__device__ inline void barrier_lds_only() {
  asm volatile("s_waitcnt lgkmcnt(0)\n\ts_barrier" ::: "memory");
}

// Wx layout: Wx[v][u*4 + nt], u = h-unit, nt in {i,f,g,o}; oj = nt*256 + u.

// ---------------------------------------------------------------------------
// K1: Wx[v][u*4+nt] = bf16( b_ih[oj] + b_hh[oj] + emb[v] . W_ih[oj] )
// R19: grid (64,4) x 49 tiles/block = 256 blocks = exactly 1 block/CU.
// Fixes the 784-block 3.06-rounds-of-256 imbalance (16 CUs ran a 4th round,
// ~25% makespan tail) and amortizes the per-block W_ih pack 3x further.
// Sibling blocks (same bx, by=0..3) have linear IDs bx+64k, 64%8==0 -> same
// XCD -> shared emb tiles are L2-local. Block 63: 38 real tiles, uniform
// break (no barrier divergence). Kept from R17: LDS-shared double-buffered
// emb pack (wave w1 packs K-chunk w1; af bytes bit-identical).
// ---------------------------------------------------------------------------
__global__ __launch_bounds__(256) void wx_k1(
    const float* __restrict__ emb, const float* __restrict__ Wih,
    const float* __restrict__ bih, const float* __restrict__ bhh,
    unsigned short* __restrict__ Wx) {
  const int w1 = threadIdx.x >> 6, lane = threadIdx.x & 63;
  const int quad = lane >> 4, n = lane & 15;
  const int combo = blockIdx.y * 4 + w1;        // 0..15 -> units combo*16..+15

  __shared__ __attribute__((aligned(16))) unsigned short etile[2][16][136]; // 8.5 KB

  float bias[4];
  short8 bfr[4][4];
#pragma unroll
  for (int nt = 0; nt < 4; ++nt) {
    const int oj = nt * 256 + combo * 16 + n;
    bias[nt] = bih[oj] + bhh[oj];
#pragma unroll
    for (int kc = 0; kc < 4; ++kc) {
      const f32x4* wp = (const f32x4*)(Wih + (size_t)oj * EMBD + kc * 32 + quad * 8);
      bfr[nt][kc] = pack2(wp[0], wp[1]);
    }
  }

  // prologue: pack tile 0 (wave w1 packs K-chunk w1)
  {
    const int vb0 = blockIdx.x * (49 * 16);
    const f32x4* ep = (const f32x4*)(emb + (size_t)(vb0 + n) * EMBD + w1 * 32 + quad * 8);
    *(short8*)&etile[0][n][w1 * 32 + quad * 8] = pack2(ep[0], ep[1]);
  }

  for (int vt = 0; vt < 49; ++vt) {
    const int vb = blockIdx.x * (49 * 16) + vt * 16;
    if (vb >= VOCAB) break;                     // uniform per block: no barrier divergence
    __syncthreads();                            // buf[vt&1] ready; buf[(vt+1)&1] free
    const int vbn = vb + 16;
    if (vt < 48 && vbn < VOCAB) {               // pack next tile into other buffer
      const f32x4* ep = (const f32x4*)(emb + (size_t)(vbn + n) * EMBD + w1 * 32 + quad * 8);
      *(short8*)&etile[(vt + 1) & 1][n][w1 * 32 + quad * 8] = pack2(ep[0], ep[1]);
    }
    short8 af[4];
#pragma unroll
    for (int kc = 0; kc < 4; ++kc)
      af[kc] = *(const short8*)&etile[vt & 1][n][kc * 32 + quad * 8];
    f32x4 acc[4];
#pragma unroll
    for (int nt = 0; nt < 4; ++nt) acc[nt] = (f32x4){0.f, 0.f, 0.f, 0.f};
#pragma unroll
    for (int kc = 0; kc < 4; ++kc)
#pragma unroll
      for (int nt = 0; nt < 4; ++nt)
        acc[nt] = __builtin_amdgcn_mfma_f32_16x16x32_bf16(af[kc], bfr[nt][kc], acc[nt], 0, 0, 0);
#pragma unroll
    for (int rr = 0; rr < 4; ++rr) {
      ushort4_t o;
#pragma unroll
      for (int nt = 0; nt < 4; ++nt) o[nt] = f2bf(acc[nt][rr] + bias[nt]);
      *(ushort4_t*)&Wx[(size_t)(vb + quad * 4 + rr) * G4 + (combo * 16 + n) * 4] = o;
    }
  }
}

// ---------------------------------------------------------------------------
// K2: LSTM recurrence — byte-identical to R13's loop (measured 892-894 us,
// reconfirmed R18). R17's fused head regressed this loop +30 us (rule-19
// co-codegen perturbation) — kept unbundled.
// Capacity lessons locked in: R14 (all-reg Whh spills; 6-reg/2-LDS optimal),
// R15 (per-step cross-WG exchange unaffordable; per-XCD L2 non-coherent).
// ---------------------------------------------------------------------------
__global__ __launch_bounds__(512, 2) void lstm_k2(
    const int* __restrict__ x, const float* __restrict__ Whh,
    const unsigned short* __restrict__ Wx,
    float* __restrict__ lastH) {               // [256][256]
  const int group = blockIdx.x;                // 64 groups of 4 batch rows
  const int rowbase = group * 4;
  const int tid = threadIdx.x;
  const int w = tid >> 6, lane = tid & 63;
  const int quad = lane >> 4, n = lane & 15;

  __shared__ __attribute__((aligned(16))) unsigned short h_lds[2][16][264];   // 16.5 KB
  __shared__ __attribute__((aligned(16))) unsigned short wlds[8][2][4][2][64][8]; // 128 KB
  __shared__ int xoff[4][TSEQ];                // 8 KB, prescaled token offsets
  __shared__ int zpos[4];

  if (tid < 4) zpos[tid] = 1 << 30;
  __syncthreads();
  // scan tokens: pad position + stage prescaled Wx row offsets in LDS
  for (int i = tid; i < 4 * TSEQ; i += 512) {
    const int row = i >> 9, tc = i & 511;
    const int tok = x[(size_t)(rowbase + row) * TSEQ + tc];
    if (tok == 0) atomicMin(&zpos[row], tc);
    xoff[row][tc] = tok * G4;
  }
  // zero BOTH h buffers (real rows 0,4,8,12 need h(0)=0; row 1 is the
  // broadcast-zero row for phantom A lanes and must stay zero forever)
  for (int i = tid; i < 2 * 16 * 264; i += 512) ((unsigned short*)h_lds)[i] = 0;

  // LDS weights: K-chunks 6,7 (B-frag layout)
#pragma unroll
  for (int gl = 0; gl < 2; ++gl)
#pragma unroll
    for (int nt = 0; nt < 4; ++nt)
#pragma unroll
      for (int kcl = 0; kcl < 2; ++kcl) {
        const int oj = nt * 256 + w * 32 + 2 * n + gl;
        const f32x4* wp = (const f32x4*)(Whh + (size_t)oj * HID + (6 + kcl) * 32 + quad * 8);
        *(short8*)&wlds[w][gl][nt][kcl][lane][0] = pack2(wp[0], wp[1]);
      }

  // register weights: K-chunks 0..5.  B[k][col=n] = Whh[oj(n)][k].
  short8 bfr[2][4][6];
#pragma unroll
  for (int gl = 0; gl < 2; ++gl)
#pragma unroll
    for (int nt = 0; nt < 4; ++nt) {
      const int oj = nt * 256 + w * 32 + 2 * n + gl;
      const float* wrow = Whh + (size_t)oj * HID;
#pragma unroll
      for (int kc = 0; kc < 6; ++kc) {
        const f32x4* wp = (const f32x4*)(wrow + kc * 32 + quad * 8);
        bfr[gl][nt][kc] = pack2(wp[0], wp[1]);
      }
    }

  float cst[2];
  cst[0] = 0.f; cst[1] = 0.f;

  __syncthreads();   // zpos, xoff, h(0), wlds ready
  const int idxq = zpos[quad] - 1;             // last valid t for this lane's row

  // per-lane constant byte offsets into h_lds
  // A-read: real lanes (n%4==0) -> row n, k-slice quad; others -> row 1 (zero,
  // broadcast). h-write: row quad*4, units u0=w*32+2n, u0+1 packed as b32.
  const int ard = ((n & 3) == 0) ? (n * 528 + quad * 16) : 528;
  const int awr = quad * 2112 + (w * 32 + 2 * n) * 2;
  const unsigned lanewx = (unsigned)((w * 32 + 2 * n) * 4);
  char* hb = (char*)&h_lds[0][0][0];
  unsigned hoff = 0;                           // read-buffer byte offset; write = hoff^8448

  // initial Wx load (t=0, both gl in one 16B load) + offset for t=1
  ushort8_t wx8 = *(const ushort8_t*)(Wx + (size_t)(unsigned)xoff[quad][0] + lanewx);
  int toko = xoff[quad][1];

  // fused pointwise (R8-validated, 5 exp + 3 rcp):
  //   c' = c*rcp(1+e^-f) + (e^{2g}-1)*rcp((1+e^-i)(e^{2g}+1))
  //   h  = (e^{2c'}-1)*rcp((1+e^-o)(e^{2c'}+1))
  for (int t = 0; t < TSEQ; ++t) {
    const int tnn = (t + 2 < TSEQ) ? (t + 2) : (TSEQ - 1);

    // acc init from prefetched Wx (has both biases); loop-local, full init:
    // only element 0 (C row quad*4) carries a real batch row.
    f32x4 acc[2][4];
#pragma unroll
    for (int gl = 0; gl < 2; ++gl)
#pragma unroll
      for (int nt = 0; nt < 4; ++nt)
        acc[gl][nt] = (f32x4){bf2f(wx8[gl * 4 + nt]), 0.f, 0.f, 0.f};

    // re-issue Wx prefetch for t+1 (consumed next step -> full-step overlap)
    wx8 = *(const ushort8_t*)(Wx + (size_t)(unsigned)toko + lanewx);
    // token offset for t+2: LDS broadcast read (lgkm, drained by the barrier)
    const int tok_next = xoff[quad][tnn];

    // merged GEMM: each A-frag read once, feeds 8 MFMAs (2gl x 4nt).
    // K-chunks 0..5 from register B-frags
#pragma unroll
    for (int kc = 0; kc < 6; ++kc) {
      const short8 a = *(const short8*)(hb + hoff + ard + kc * 64);
#pragma unroll
      for (int gl = 0; gl < 2; ++gl)
#pragma unroll
        for (int nt = 0; nt < 4; ++nt)
          acc[gl][nt] = __builtin_amdgcn_mfma_f32_16x16x32_bf16(a, bfr[gl][nt][kc], acc[gl][nt], 0, 0, 0);
    }
    // K-chunks 6..7 from LDS B-frags
#pragma unroll
    for (int kcl = 0; kcl < 2; ++kcl) {
      const short8 a = *(const short8*)(hb + hoff + ard + (6 + kcl) * 64);
#pragma unroll
      for (int gl = 0; gl < 2; ++gl)
#pragma unroll
        for (int nt = 0; nt < 4; ++nt) {
          const short8 b = *(const short8*)&wlds[w][gl][nt][kcl][lane][0];
          acc[gl][nt] = __builtin_amdgcn_mfma_f32_16x16x32_bf16(a, b, acc[gl][nt], 0, 0, 0);
        }
    }

    toko = tok_next;

    // fused pointwise, both gl, then one packed h-write
    float hv2[2];
#pragma unroll
    for (int gl = 0; gl < 2; ++gl) {
      const float ei = __expf(-acc[gl][0][0]), ef = __expf(-acc[gl][1][0]);
      const float eg2 = __expf(2.0f * acc[gl][2][0]), eo = __expf(-acc[gl][3][0]);
      const float r1 = __builtin_amdgcn_rcpf(1.0f + ef);
      const float r2 = __builtin_amdgcn_rcpf((1.0f + ei) * (eg2 + 1.0f));
      const float ci = cst[gl] * r1 + (eg2 - 1.0f) * r2;
      cst[gl] = ci;
      const float ec2 = __expf(2.0f * ci);
      const float r3 = __builtin_amdgcn_rcpf((1.0f + eo) * (ec2 + 1.0f));
      hv2[gl] = (ec2 - 1.0f) * r3;
    }
    const unsigned pk = (unsigned)f2bf(hv2[0]) | ((unsigned)f2bf(hv2[1]) << 16);
    *(unsigned*)(hb + (hoff ^ 8448u) + awr) = pk;

    // gathered last-valid h: fires once per row over the 512 steps
    if (t == idxq) {
      const size_t o0 = (size_t)(rowbase + quad) * HID + (w * 32 + 2 * n);
      lastH[o0] = hv2[0];
      lastH[o0 + 1] = hv2[1];
    }

    hoff ^= 8448u;
    barrier_lds_only();  // h(t+1) complete; global prefetches stay in flight
  }
}

// ---------------------------------------------------------------------------
// K3: logits + softmax. One wave per batch row; lane j = output j.
// ---------------------------------------------------------------------------
__global__ __launch_bounds__(64) void head_k3(
    const float* __restrict__ lastH, const float* __restrict__ Wout,
    const float* __restrict__ bout, float* __restrict__ out) {
  const int b = blockIdx.x, j = threadIdx.x;
  const f32x4* hv = (const f32x4*)(lastH + (size_t)b * HID);
  const f32x4* wv = (const f32x4*)(Wout + (size_t)j * HID);
  float acc = bout[j];
#pragma unroll 8
  for (int k = 0; k < HID / 4; ++k) {
    const f32x4 a = hv[k], ww = wv[k];
    acc += a[0] * ww[0] + a[1] * ww[1] + a[2] * ww[2] + a[3] * ww[3];
  }
  float m = acc;
  for (int s = 32; s > 0; s >>= 1) m = fmaxf(m, __shfl_xor(m, s, 64));
  const float e = __expf(acc - m);
  float ssum = e;
  for (int s = 32; s > 0; s >>= 1) ssum += __shfl_xor(ssum, s, 64);
  out[(size_t)b * OUTD + j] = e / ssum;
}

// ---------------------------------------------------------------------------
extern "C" void kernel_launch(void* const* d_in, const int* in_sizes, int n_in,
                              void* d_out, int out_size, void* d_ws, size_t ws_size,
                              hipStream_t stream) {
  const int*   x    = (const int*)d_in[0];
  const float* emb  = (const float*)d_in[1];
  const float* Wih  = (const float*)d_in[2];
  const float* Whh  = (const float*)d_in[3];
  const float* bih  = (const float*)d_in[4];
  const float* bhh  = (const float*)d_in[5];
  const float* Wout = (const float*)d_in[6];
  const float* bout = (const float*)d_in[7];
  float* out = (float*)d_out;

  // workspace carve (~97.9 MiB)
  char* ws = (char*)d_ws;
  unsigned short* Wx = (unsigned short*)ws;                 // 102,400,000 B
  float* lastH = (float*)(ws + 102400000);                  // 262,144 B

  hipLaunchKernelGGL(wx_k1, dim3(64, 4), dim3(256), 0, stream,
                     emb, Wih, bih, bhh, Wx);
  hipLaunchKernelGGL(lstm_k2, dim3(64), dim3(512), 0, stream,
                     x, Whh, Wx, lastH);
  hipLaunchKernelGGL(head_k3, dim3(BATCH), dim3(OUTD), 0, stream,
                     lastH, Wout, bout, out);
}

// Round 11
// 1017.435 us; speedup vs baseline: 1.0044x; 1.0044x over previous
//
#include <hip/hip_runtime.h>
#include <stdint.h>

// Problem constants
#define VOCAB 50000
#define EMBD  128
#define HID   256
#define G4    1024   // 4*HID
#define BATCH 256
#define TSEQ  512
#define OUTD  64

typedef __attribute__((ext_vector_type(4))) float f32x4;
typedef __attribute__((ext_vector_type(8))) short short8;
typedef __attribute__((ext_vector_type(4))) unsigned short ushort4_t;
typedef __attribute__((ext_vector_type(8))) unsigned short ushort8_t;

__device__ inline unsigned short f2bf(float f) {
  unsigned u = __float_as_uint(f);
  u += 0x7fffu + ((u >> 16) & 1u);     // round-nearest-even
  return (unsigned short)(u >> 16);
}
__device__ inline float bf2f(unsigned short u) {
  return __uint_as_float(((unsigned)u) << 16);
}
__device__ inline short8 pack2(f32x4 a, f32x4 b) {
  short8 r;
  r[0] = (short)f2bf(a[0]); r[1] = (short)f2bf(a[1]);
  r[2] = (short)f2bf(a[2]); r[3] = (short)f2bf(a[3]);
  r[4] = (short)f2bf(b[0]); r[5] = (short)f2bf(b[1]);
  r[6] = (short)f2bf(b[2]); r[7] = (short)f2bf(b[3]);
  return r;
}

// LDS-only barrier: h double-buffer needs only LDS ordering; global prefetch
// loads stay in flight across it.
__device__ inline void barrier_lds_only() {
  asm volatile("s_waitcnt lgkmcnt(0)\n\ts_barrier" ::: "memory");
}

// Wx layout: Wx[v][u*4 + nt], u = h-unit, nt in {i,f,g,o}; oj = nt*256 + u.

// ---------------------------------------------------------------------------
// K1: Wx[v][u*4+nt] = bf16( b_ih[oj] + b_hh[oj] + emb[v] . W_ih[oj] )
// R20: geometry reverted to R18's measured-best (196,4) x 16 tiles — R19
// proved co-residency (2-4 blocks/CU at 784 blocks) beats perfect balance
// (256 blocks = 1/CU exposed the serial per-tile latency chain, +16 us).
// New: NON-TEMPORAL Wx stores — 102 MB written once, consumed next kernel,
// 3x aggregate L2; nt skips L2 write-allocate on the store path.
// Kept from R17: LDS-shared double-buffered emb pack (bit-identical af).
// ---------------------------------------------------------------------------
__global__ __launch_bounds__(256) void wx_k1(
    const float* __restrict__ emb, const float* __restrict__ Wih,
    const float* __restrict__ bih, const float* __restrict__ bhh,
    unsigned short* __restrict__ Wx) {
  const int w1 = threadIdx.x >> 6, lane = threadIdx.x & 63;
  const int quad = lane >> 4, n = lane & 15;
  const int combo = blockIdx.y * 4 + w1;        // 0..15 -> units combo*16..+15

  __shared__ __attribute__((aligned(16))) unsigned short etile[2][16][136]; // 8.5 KB

  float bias[4];
  short8 bfr[4][4];
#pragma unroll
  for (int nt = 0; nt < 4; ++nt) {
    const int oj = nt * 256 + combo * 16 + n;
    bias[nt] = bih[oj] + bhh[oj];
#pragma unroll
    for (int kc = 0; kc < 4; ++kc) {
      const f32x4* wp = (const f32x4*)(Wih + (size_t)oj * EMBD + kc * 32 + quad * 8);
      bfr[nt][kc] = pack2(wp[0], wp[1]);
    }
  }

  // prologue: pack tile 0 (wave w1 packs K-chunk w1)
  {
    const int vb0 = blockIdx.x * 256;
    const f32x4* ep = (const f32x4*)(emb + (size_t)(vb0 + n) * EMBD + w1 * 32 + quad * 8);
    *(short8*)&etile[0][n][w1 * 32 + quad * 8] = pack2(ep[0], ep[1]);
  }

  for (int vt = 0; vt < 16; ++vt) {
    const int vb = blockIdx.x * 256 + vt * 16;
    if (vb >= VOCAB) break;                     // uniform per block: no barrier divergence
    __syncthreads();                            // buf[vt&1] ready; buf[(vt+1)&1] free
    const int vbn = vb + 16;
    if (vt < 15 && vbn < VOCAB) {               // pack next tile into other buffer
      const f32x4* ep = (const f32x4*)(emb + (size_t)(vbn + n) * EMBD + w1 * 32 + quad * 8);
      *(short8*)&etile[(vt + 1) & 1][n][w1 * 32 + quad * 8] = pack2(ep[0], ep[1]);
    }
    short8 af[4];
#pragma unroll
    for (int kc = 0; kc < 4; ++kc)
      af[kc] = *(const short8*)&etile[vt & 1][n][kc * 32 + quad * 8];
    f32x4 acc[4];
#pragma unroll
    for (int nt = 0; nt < 4; ++nt) acc[nt] = (f32x4){0.f, 0.f, 0.f, 0.f};
#pragma unroll
    for (int kc = 0; kc < 4; ++kc)
#pragma unroll
      for (int nt = 0; nt < 4; ++nt)
        acc[nt] = __builtin_amdgcn_mfma_f32_16x16x32_bf16(af[kc], bfr[nt][kc], acc[nt], 0, 0, 0);
#pragma unroll
    for (int rr = 0; rr < 4; ++rr) {
      ushort4_t o;
#pragma unroll
      for (int nt = 0; nt < 4; ++nt) o[nt] = f2bf(acc[nt][rr] + bias[nt]);
      __builtin_nontemporal_store(
          o, (ushort4_t*)&Wx[(size_t)(vb + quad * 4 + rr) * G4 + (combo * 16 + n) * 4]);
    }
  }
}

// ---------------------------------------------------------------------------
// K2: LSTM recurrence — byte-identical to R13's loop (892-896 us, confirmed
// R13/R16/R18/R19). R17's fused head regressed this loop +30 us (rule-19
// co-codegen perturbation) — kept unbundled.
// Capacity lessons locked in: R14 (all-reg Whh spills; 6-reg/2-LDS optimal),
// R15 (per-step cross-WG exchange unaffordable; per-XCD L2 non-coherent).
// ---------------------------------------------------------------------------
__global__ __launch_bounds__(512, 2) void lstm_k2(
    const int* __restrict__ x, const float* __restrict__ Whh,
    const unsigned short* __restrict__ Wx,
    float* __restrict__ lastH) {               // [256][256]
  const int group = blockIdx.x;                // 64 groups of 4 batch rows
  const int rowbase = group * 4;
  const int tid = threadIdx.x;
  const int w = tid >> 6, lane = tid & 63;
  const int quad = lane >> 4, n = lane & 15;

  __shared__ __attribute__((aligned(16))) unsigned short h_lds[2][16][264];   // 16.5 KB
  __shared__ __attribute__((aligned(16))) unsigned short wlds[8][2][4][2][64][8]; // 128 KB
  __shared__ int xoff[4][TSEQ];                // 8 KB, prescaled token offsets
  __shared__ int zpos[4];

  if (tid < 4) zpos[tid] = 1 << 30;
  __syncthreads();
  // scan tokens: pad position + stage prescaled Wx row offsets in LDS
  for (int i = tid; i < 4 * TSEQ; i += 512) {
    const int row = i >> 9, tc = i & 511;
    const int tok = x[(size_t)(rowbase + row) * TSEQ + tc];
    if (tok == 0) atomicMin(&zpos[row], tc);
    xoff[row][tc] = tok * G4;
  }
  // zero BOTH h buffers (real rows 0,4,8,12 need h(0)=0; row 1 is the
  // broadcast-zero row for phantom A lanes and must stay zero forever)
  for (int i = tid; i < 2 * 16 * 264; i += 512) ((unsigned short*)h_lds)[i] = 0;

  // LDS weights: K-chunks 6,7 (B-frag layout)
#pragma unroll
  for (int gl = 0; gl < 2; ++gl)
#pragma unroll
    for (int nt = 0; nt < 4; ++nt)
#pragma unroll
      for (int kcl = 0; kcl < 2; ++kcl) {
        const int oj = nt * 256 + w * 32 + 2 * n + gl;
        const f32x4* wp = (const f32x4*)(Whh + (size_t)oj * HID + (6 + kcl) * 32 + quad * 8);
        *(short8*)&wlds[w][gl][nt][kcl][lane][0] = pack2(wp[0], wp[1]);
      }

  // register weights: K-chunks 0..5.  B[k][col=n] = Whh[oj(n)][k].
  short8 bfr[2][4][6];
#pragma unroll
  for (int gl = 0; gl < 2; ++gl)
#pragma unroll
    for (int nt = 0; nt < 4; ++nt) {
      const int oj = nt * 256 + w * 32 + 2 * n + gl;
      const float* wrow = Whh + (size_t)oj * HID;
#pragma unroll
      for (int kc = 0; kc < 6; ++kc) {
        const f32x4* wp = (const f32x4*)(wrow + kc * 32 + quad * 8);
        bfr[gl][nt][kc] = pack2(wp[0], wp[1]);
      }
    }

  float cst[2];
  cst[0] = 0.f; cst[1] = 0.f;

  __syncthreads();   // zpos, xoff, h(0), wlds ready
  const int idxq = zpos[quad] - 1;             // last valid t for this lane's row

  // per-lane constant byte offsets into h_lds
  // A-read: real lanes (n%4==0) -> row n, k-slice quad; others -> row 1 (zero,
  // broadcast). h-write: row quad*4, units u0=w*32+2n, u0+1 packed as b32.
  const int ard = ((n & 3) == 0) ? (n * 528 + quad * 16) : 528;
  const int awr = quad * 2112 + (w * 32 + 2 * n) * 2;
  const unsigned lanewx = (unsigned)((w * 32 + 2 * n) * 4);
  char* hb = (char*)&h_lds[0][0][0];
  unsigned hoff = 0;                           // read-buffer byte offset; write = hoff^8448

  // initial Wx load (t=0, both gl in one 16B load) + offset for t=1
  ushort8_t wx8 = *(const ushort8_t*)(Wx + (size_t)(unsigned)xoff[quad][0] + lanewx);
  int toko = xoff[quad][1];

  // fused pointwise (R8-validated, 5 exp + 3 rcp):
  //   c' = c*rcp(1+e^-f) + (e^{2g}-1)*rcp((1+e^-i)(e^{2g}+1))
  //   h  = (e^{2c'}-1)*rcp((1+e^-o)(e^{2c'}+1))
  for (int t = 0; t < TSEQ; ++t) {
    const int tnn = (t + 2 < TSEQ) ? (t + 2) : (TSEQ - 1);

    // acc init from prefetched Wx (has both biases); loop-local, full init:
    // only element 0 (C row quad*4) carries a real batch row.
    f32x4 acc[2][4];
#pragma unroll
    for (int gl = 0; gl < 2; ++gl)
#pragma unroll
      for (int nt = 0; nt < 4; ++nt)
        acc[gl][nt] = (f32x4){bf2f(wx8[gl * 4 + nt]), 0.f, 0.f, 0.f};

    // re-issue Wx prefetch for t+1 (consumed next step -> full-step overlap)
    wx8 = *(const ushort8_t*)(Wx + (size_t)(unsigned)toko + lanewx);
    // token offset for t+2: LDS broadcast read (lgkm, drained by the barrier)
    const int tok_next = xoff[quad][tnn];

    // merged GEMM: each A-frag read once, feeds 8 MFMAs (2gl x 4nt).
    // K-chunks 0..5 from register B-frags
#pragma unroll
    for (int kc = 0; kc < 6; ++kc) {
      const short8 a = *(const short8*)(hb + hoff + ard + kc * 64);
#pragma unroll
      for (int gl = 0; gl < 2; ++gl)
#pragma unroll
        for (int nt = 0; nt < 4; ++nt)
          acc[gl][nt] = __builtin_amdgcn_mfma_f32_16x16x32_bf16(a, bfr[gl][nt][kc], acc[gl][nt], 0, 0, 0);
    }
    // K-chunks 6..7 from LDS B-frags
#pragma unroll
    for (int kcl = 0; kcl < 2; ++kcl) {
      const short8 a = *(const short8*)(hb + hoff + ard + (6 + kcl) * 64);
#pragma unroll
      for (int gl = 0; gl < 2; ++gl)
#pragma unroll
        for (int nt = 0; nt < 4; ++nt) {
          const short8 b = *(const short8*)&wlds[w][gl][nt][kcl][lane][0];
          acc[gl][nt] = __builtin_amdgcn_mfma_f32_16x16x32_bf16(a, b, acc[gl][nt], 0, 0, 0);
        }
    }

    toko = tok_next;

    // fused pointwise, both gl, then one packed h-write
    float hv2[2];
#pragma unroll
    for (int gl = 0; gl < 2; ++gl) {
      const float ei = __expf(-acc[gl][0][0]), ef = __expf(-acc[gl][1][0]);
      const float eg2 = __expf(2.0f * acc[gl][2][0]), eo = __expf(-acc[gl][3][0]);
      const float r1 = __builtin_amdgcn_rcpf(1.0f + ef);
      const float r2 = __builtin_amdgcn_rcpf((1.0f + ei) * (eg2 + 1.0f));
      const float ci = cst[gl] * r1 + (eg2 - 1.0f) * r2;
      cst[gl] = ci;
      const float ec2 = __expf(2.0f * ci);
      const float r3 = __builtin_amdgcn_rcpf((1.0f + eo) * (ec2 + 1.0f));
      hv2[gl] = (ec2 - 1.0f) * r3;
    }
    const unsigned pk = (unsigned)f2bf(hv2[0]) | ((unsigned)f2bf(hv2[1]) << 16);
    *(unsigned*)(hb + (hoff ^ 8448u) + awr) = pk;

    // gathered last-valid h: fires once per row over the 512 steps
    if (t == idxq) {
      const size_t o0 = (size_t)(rowbase + quad) * HID + (w * 32 + 2 * n);
      lastH[o0] = hv2[0];
      lastH[o0 + 1] = hv2[1];
    }

    hoff ^= 8448u;
    barrier_lds_only();  // h(t+1) complete; global prefetches stay in flight
  }
}

// ---------------------------------------------------------------------------
// K3: logits + softmax. One wave per batch row; lane j = output j.
// ---------------------------------------------------------------------------
__global__ __launch_bounds__(64) void head_k3(
    const float* __restrict__ lastH, const float* __restrict__ Wout,
    const float* __restrict__ bout, float* __restrict__ out) {
  const int b = blockIdx.x, j = threadIdx.x;
  const f32x4* hv = (const f32x4*)(lastH + (size_t)b * HID);
  const f32x4* wv = (const f32x4*)(Wout + (size_t)j * HID);
  float acc = bout[j];
#pragma unroll 8
  for (int k = 0; k < HID / 4; ++k) {
    const f32x4 a = hv[k], ww = wv[k];
    acc += a[0] * ww[0] + a[1] * ww[1] + a[2] * ww[2] + a[3] * ww[3];
  }
  float m = acc;
  for (int s = 32; s > 0; s >>= 1) m = fmaxf(m, __shfl_xor(m, s, 64));
  const float e = __expf(acc - m);
  float ssum = e;
  for (int s = 32; s > 0; s >>= 1) ssum += __shfl_xor(ssum, s, 64);
  out[(size_t)b * OUTD + j] = e / ssum;
}

// ---------------------------------------------------------------------------
extern "C" void kernel_launch(void* const* d_in, const int* in_sizes, int n_in,
                              void* d_out, int out_size, void* d_ws, size_t ws_size,
                              hipStream_t stream) {
  const int*   x    = (const int*)d_in[0];
  const float* emb  = (const float*)d_in[1];
  const float* Wih  = (const float*)d_in[2];
  const float* Whh  = (const float*)d_in[3];
  const float* bih  = (const float*)d_in[4];
  const float* bhh  = (const float*)d_in[5];
  const float* Wout = (const float*)d_in[6];
  const float* bout = (const float*)d_in[7];
  float* out = (float*)d_out;

  // workspace carve (~97.9 MiB)
  char* ws = (char*)d_ws;
  unsigned short* Wx = (unsigned short*)ws;                 // 102,400,000 B
  float* lastH = (float*)(ws + 102400000);                  // 262,144 B

  hipLaunchKernelGGL(wx_k1, dim3(196, 4), dim3(256), 0, stream,
                     emb, Wih, bih, bhh, Wx);
  hipLaunchKernelGGL(lstm_k2, dim3(64), dim3(512), 0, stream,
                     x, Whh, Wx, lastH);
  hipLaunchKernelGGL(head_k3, dim3(BATCH), dim3(OUTD), 0, stream,
                     lastH, Wout, bout, out);
}

// Round 12
// 1012.806 us; speedup vs baseline: 1.0089x; 1.0046x over previous
//
#include <hip/hip_runtime.h>
#include <stdint.h>

// Problem constants
#define VOCAB 50000
#define EMBD  128
#define HID   256
#define G4    1024   // 4*HID
#define BATCH 256
#define TSEQ  512
#define OUTD  64

typedef __attribute__((ext_vector_type(4))) float f32x4;
typedef __attribute__((ext_vector_type(8))) short short8;
typedef __attribute__((ext_vector_type(4))) unsigned short ushort4_t;
typedef __attribute__((ext_vector_type(8))) unsigned short ushort8_t;

__device__ inline unsigned short f2bf(float f) {
  unsigned u = __float_as_uint(f);
  u += 0x7fffu + ((u >> 16) & 1u);     // round-nearest-even
  return (unsigned short)(u >> 16);
}
__device__ inline float bf2f(unsigned short u) {
  return __uint_as_float(((unsigned)u) << 16);
}
__device__ inline short8 pack2(f32x4 a, f32x4 b) {
  short8 r;
  r[0] = (short)f2bf(a[0]); r[1] = (short)f2bf(a[1]);
  r[2] = (short)f2bf(a[2]); r[3] = (short)f2bf(a[3]);
  r[4] = (short)f2bf(b[0]); r[5] = (short)f2bf(b[1]);
  r[6] = (short)f2bf(b[2]); r[7] = (short)f2bf(b[3]);
  return r;
}

// LDS-only barrier: h double-buffer needs only LDS ordering; global prefetch
// loads stay in flight across it.
__device__ inline void barrier_lds_only() {
  asm volatile("s_waitcnt lgkmcnt(0)\n\ts_barrier" ::: "memory");
}

// Wx layout: Wx[v][u*4 + nt], u = h-unit, nt in {i,f,g,o}; oj = nt*256 + u.

// ---------------------------------------------------------------------------
// K1: Wx[v][u*4+nt] = bf16( b_ih[oj] + b_hh[oj] + emb[v] . W_ih[oj] )
// R21 = R18 exact (best measured, 1006.1 us total): (196,4) x 16 tiles,
// LDS-shared double-buffered emb pack, PLAIN stores (R20's nt store was
// neutral-to-negative, reverted). R19 proved co-residency (2-4 blocks/CU)
// beats perfect balance; R17 proved the shared pack (+32 us vs per-wave).
// ---------------------------------------------------------------------------
__global__ __launch_bounds__(256) void wx_k1(
    const float* __restrict__ emb, const float* __restrict__ Wih,
    const float* __restrict__ bih, const float* __restrict__ bhh,
    unsigned short* __restrict__ Wx) {
  const int w1 = threadIdx.x >> 6, lane = threadIdx.x & 63;
  const int quad = lane >> 4, n = lane & 15;
  const int combo = blockIdx.y * 4 + w1;        // 0..15 -> units combo*16..+15

  __shared__ __attribute__((aligned(16))) unsigned short etile[2][16][136]; // 8.5 KB

  float bias[4];
  short8 bfr[4][4];
#pragma unroll
  for (int nt = 0; nt < 4; ++nt) {
    const int oj = nt * 256 + combo * 16 + n;
    bias[nt] = bih[oj] + bhh[oj];
#pragma unroll
    for (int kc = 0; kc < 4; ++kc) {
      const f32x4* wp = (const f32x4*)(Wih + (size_t)oj * EMBD + kc * 32 + quad * 8);
      bfr[nt][kc] = pack2(wp[0], wp[1]);
    }
  }

  // prologue: pack tile 0 (wave w1 packs K-chunk w1)
  {
    const int vb0 = blockIdx.x * 256;
    const f32x4* ep = (const f32x4*)(emb + (size_t)(vb0 + n) * EMBD + w1 * 32 + quad * 8);
    *(short8*)&etile[0][n][w1 * 32 + quad * 8] = pack2(ep[0], ep[1]);
  }

  for (int vt = 0; vt < 16; ++vt) {
    const int vb = blockIdx.x * 256 + vt * 16;
    if (vb >= VOCAB) break;                     // uniform per block: no barrier divergence
    __syncthreads();                            // buf[vt&1] ready; buf[(vt+1)&1] free
    const int vbn = vb + 16;
    if (vt < 15 && vbn < VOCAB) {               // pack next tile into other buffer
      const f32x4* ep = (const f32x4*)(emb + (size_t)(vbn + n) * EMBD + w1 * 32 + quad * 8);
      *(short8*)&etile[(vt + 1) & 1][n][w1 * 32 + quad * 8] = pack2(ep[0], ep[1]);
    }
    short8 af[4];
#pragma unroll
    for (int kc = 0; kc < 4; ++kc)
      af[kc] = *(const short8*)&etile[vt & 1][n][kc * 32 + quad * 8];
    f32x4 acc[4];
#pragma unroll
    for (int nt = 0; nt < 4; ++nt) acc[nt] = (f32x4){0.f, 0.f, 0.f, 0.f};
#pragma unroll
    for (int kc = 0; kc < 4; ++kc)
#pragma unroll
      for (int nt = 0; nt < 4; ++nt)
        acc[nt] = __builtin_amdgcn_mfma_f32_16x16x32_bf16(af[kc], bfr[nt][kc], acc[nt], 0, 0, 0);
#pragma unroll
    for (int rr = 0; rr < 4; ++rr) {
      ushort4_t o;
#pragma unroll
      for (int nt = 0; nt < 4; ++nt) o[nt] = f2bf(acc[nt][rr] + bias[nt]);
      *(ushort4_t*)&Wx[(size_t)(vb + quad * 4 + rr) * G4 + (combo * 16 + n) * 4] = o;
    }
  }
}

// ---------------------------------------------------------------------------
// K2: LSTM recurrence — byte-identical to R13's loop (892-899 us, confirmed
// across R13/R16/R18/R19/R20 containers). R17's fused head regressed this
// loop +30 us (rule-19 co-codegen perturbation) — kept unbundled.
// Capacity lessons locked in: R14 (all-reg Whh spills; weights/wave = 256
// regs/lane invariant vs the 256-reg cap; 6-reg/2-LDS optimal), R15
// (per-step cross-WG exchange unaffordable; per-XCD L2 non-coherent).
// ---------------------------------------------------------------------------
__global__ __launch_bounds__(512, 2) void lstm_k2(
    const int* __restrict__ x, const float* __restrict__ Whh,
    const unsigned short* __restrict__ Wx,
    float* __restrict__ lastH) {               // [256][256]
  const int group = blockIdx.x;                // 64 groups of 4 batch rows
  const int rowbase = group * 4;
  const int tid = threadIdx.x;
  const int w = tid >> 6, lane = tid & 63;
  const int quad = lane >> 4, n = lane & 15;

  __shared__ __attribute__((aligned(16))) unsigned short h_lds[2][16][264];   // 16.5 KB
  __shared__ __attribute__((aligned(16))) unsigned short wlds[8][2][4][2][64][8]; // 128 KB
  __shared__ int xoff[4][TSEQ];                // 8 KB, prescaled token offsets
  __shared__ int zpos[4];

  if (tid < 4) zpos[tid] = 1 << 30;
  __syncthreads();
  // scan tokens: pad position + stage prescaled Wx row offsets in LDS
  for (int i = tid; i < 4 * TSEQ; i += 512) {
    const int row = i >> 9, tc = i & 511;
    const int tok = x[(size_t)(rowbase + row) * TSEQ + tc];
    if (tok == 0) atomicMin(&zpos[row], tc);
    xoff[row][tc] = tok * G4;
  }
  // zero BOTH h buffers (real rows 0,4,8,12 need h(0)=0; row 1 is the
  // broadcast-zero row for phantom A lanes and must stay zero forever)
  for (int i = tid; i < 2 * 16 * 264; i += 512) ((unsigned short*)h_lds)[i] = 0;

  // LDS weights: K-chunks 6,7 (B-frag layout)
#pragma unroll
  for (int gl = 0; gl < 2; ++gl)
#pragma unroll
    for (int nt = 0; nt < 4; ++nt)
#pragma unroll
      for (int kcl = 0; kcl < 2; ++kcl) {
        const int oj = nt * 256 + w * 32 + 2 * n + gl;
        const f32x4* wp = (const f32x4*)(Whh + (size_t)oj * HID + (6 + kcl) * 32 + quad * 8);
        *(short8*)&wlds[w][gl][nt][kcl][lane][0] = pack2(wp[0], wp[1]);
      }

  // register weights: K-chunks 0..5.  B[k][col=n] = Whh[oj(n)][k].
  short8 bfr[2][4][6];
#pragma unroll
  for (int gl = 0; gl < 2; ++gl)
#pragma unroll
    for (int nt = 0; nt < 4; ++nt) {
      const int oj = nt * 256 + w * 32 + 2 * n + gl;
      const float* wrow = Whh + (size_t)oj * HID;
#pragma unroll
      for (int kc = 0; kc < 6; ++kc) {
        const f32x4* wp = (const f32x4*)(wrow + kc * 32 + quad * 8);
        bfr[gl][nt][kc] = pack2(wp[0], wp[1]);
      }
    }

  float cst[2];
  cst[0] = 0.f; cst[1] = 0.f;

  __syncthreads();   // zpos, xoff, h(0), wlds ready
  const int idxq = zpos[quad] - 1;             // last valid t for this lane's row

  // per-lane constant byte offsets into h_lds
  // A-read: real lanes (n%4==0) -> row n, k-slice quad; others -> row 1 (zero,
  // broadcast). h-write: row quad*4, units u0=w*32+2n, u0+1 packed as b32.
  const int ard = ((n & 3) == 0) ? (n * 528 + quad * 16) : 528;
  const int awr = quad * 2112 + (w * 32 + 2 * n) * 2;
  const unsigned lanewx = (unsigned)((w * 32 + 2 * n) * 4);
  char* hb = (char*)&h_lds[0][0][0];
  unsigned hoff = 0;                           // read-buffer byte offset; write = hoff^8448

  // initial Wx load (t=0, both gl in one 16B load) + offset for t=1
  ushort8_t wx8 = *(const ushort8_t*)(Wx + (size_t)(unsigned)xoff[quad][0] + lanewx);
  int toko = xoff[quad][1];

  // fused pointwise (R8-validated, 5 exp + 3 rcp):
  //   c' = c*rcp(1+e^-f) + (e^{2g}-1)*rcp((1+e^-i)(e^{2g}+1))
  //   h  = (e^{2c'}-1)*rcp((1+e^-o)(e^{2c'}+1))
  for (int t = 0; t < TSEQ; ++t) {
    const int tnn = (t + 2 < TSEQ) ? (t + 2) : (TSEQ - 1);

    // acc init from prefetched Wx (has both biases); loop-local, full init:
    // only element 0 (C row quad*4) carries a real batch row.
    f32x4 acc[2][4];
#pragma unroll
    for (int gl = 0; gl < 2; ++gl)
#pragma unroll
      for (int nt = 0; nt < 4; ++nt)
        acc[gl][nt] = (f32x4){bf2f(wx8[gl * 4 + nt]), 0.f, 0.f, 0.f};

    // re-issue Wx prefetch for t+1 (consumed next step -> full-step overlap)
    wx8 = *(const ushort8_t*)(Wx + (size_t)(unsigned)toko + lanewx);
    // token offset for t+2: LDS broadcast read (lgkm, drained by the barrier)
    const int tok_next = xoff[quad][tnn];

    // merged GEMM: each A-frag read once, feeds 8 MFMAs (2gl x 4nt).
    // K-chunks 0..5 from register B-frags
#pragma unroll
    for (int kc = 0; kc < 6; ++kc) {
      const short8 a = *(const short8*)(hb + hoff + ard + kc * 64);
#pragma unroll
      for (int gl = 0; gl < 2; ++gl)
#pragma unroll
        for (int nt = 0; nt < 4; ++nt)
          acc[gl][nt] = __builtin_amdgcn_mfma_f32_16x16x32_bf16(a, bfr[gl][nt][kc], acc[gl][nt], 0, 0, 0);
    }
    // K-chunks 6..7 from LDS B-frags
#pragma unroll
    for (int kcl = 0; kcl < 2; ++kcl) {
      const short8 a = *(const short8*)(hb + hoff + ard + (6 + kcl) * 64);
#pragma unroll
      for (int gl = 0; gl < 2; ++gl)
#pragma unroll
        for (int nt = 0; nt < 4; ++nt) {
          const short8 b = *(const short8*)&wlds[w][gl][nt][kcl][lane][0];
          acc[gl][nt] = __builtin_amdgcn_mfma_f32_16x16x32_bf16(a, b, acc[gl][nt], 0, 0, 0);
        }
    }

    toko = tok_next;

    // fused pointwise, both gl, then one packed h-write
    float hv2[2];
#pragma unroll
    for (int gl = 0; gl < 2; ++gl) {
      const float ei = __expf(-acc[gl][0][0]), ef = __expf(-acc[gl][1][0]);
      const float eg2 = __expf(2.0f * acc[gl][2][0]), eo = __expf(-acc[gl][3][0]);
      const float r1 = __builtin_amdgcn_rcpf(1.0f + ef);
      const float r2 = __builtin_amdgcn_rcpf((1.0f + ei) * (eg2 + 1.0f));
      const float ci = cst[gl] * r1 + (eg2 - 1.0f) * r2;
      cst[gl] = ci;
      const float ec2 = __expf(2.0f * ci);
      const float r3 = __builtin_amdgcn_rcpf((1.0f + eo) * (ec2 + 1.0f));
      hv2[gl] = (ec2 - 1.0f) * r3;
    }
    const unsigned pk = (unsigned)f2bf(hv2[0]) | ((unsigned)f2bf(hv2[1]) << 16);
    *(unsigned*)(hb + (hoff ^ 8448u) + awr) = pk;

    // gathered last-valid h: fires once per row over the 512 steps
    if (t == idxq) {
      const size_t o0 = (size_t)(rowbase + quad) * HID + (w * 32 + 2 * n);
      lastH[o0] = hv2[0];
      lastH[o0 + 1] = hv2[1];
    }

    hoff ^= 8448u;
    barrier_lds_only();  // h(t+1) complete; global prefetches stay in flight
  }
}

// ---------------------------------------------------------------------------
// K3: logits + softmax. One wave per batch row; lane j = output j.
// ---------------------------------------------------------------------------
__global__ __launch_bounds__(64) void head_k3(
    const float* __restrict__ lastH, const float* __restrict__ Wout,
    const float* __restrict__ bout, float* __restrict__ out) {
  const int b = blockIdx.x, j = threadIdx.x;
  const f32x4* hv = (const f32x4*)(lastH + (size_t)b * HID);
  const f32x4* wv = (const f32x4*)(Wout + (size_t)j * HID);
  float acc = bout[j];
#pragma unroll 8
  for (int k = 0; k < HID / 4; ++k) {
    const f32x4 a = hv[k], ww = wv[k];
    acc += a[0] * ww[0] + a[1] * ww[1] + a[2] * ww[2] + a[3] * ww[3];
  }
  float m = acc;
  for (int s = 32; s > 0; s >>= 1) m = fmaxf(m, __shfl_xor(m, s, 64));
  const float e = __expf(acc - m);
  float ssum = e;
  for (int s = 32; s > 0; s >>= 1) ssum += __shfl_xor(ssum, s, 64);
  out[(size_t)b * OUTD + j] = e / ssum;
}

// ---------------------------------------------------------------------------
extern "C" void kernel_launch(void* const* d_in, const int* in_sizes, int n_in,
                              void* d_out, int out_size, void* d_ws, size_t ws_size,
                              hipStream_t stream) {
  const int*   x    = (const int*)d_in[0];
  const float* emb  = (const float*)d_in[1];
  const float* Wih  = (const float*)d_in[2];
  const float* Whh  = (const float*)d_in[3];
  const float* bih  = (const float*)d_in[4];
  const float* bhh  = (const float*)d_in[5];
  const float* Wout = (const float*)d_in[6];
  const float* bout = (const float*)d_in[7];
  float* out = (float*)d_out;

  // workspace carve (~97.9 MiB)
  char* ws = (char*)d_ws;
  unsigned short* Wx = (unsigned short*)ws;                 // 102,400,000 B
  float* lastH = (float*)(ws + 102400000);                  // 262,144 B

  hipLaunchKernelGGL(wx_k1, dim3(196, 4), dim3(256), 0, stream,
                     emb, Wih, bih, bhh, Wx);
  hipLaunchKernelGGL(lstm_k2, dim3(64), dim3(512), 0, stream,
                     x, Whh, Wx, lastH);
  hipLaunchKernelGGL(head_k3, dim3(BATCH), dim3(OUTD), 0, stream,
                     lastH, Wout, bout, out);
}